// Round 1
// baseline (388.392 us; speedup 1.0000x reference)
//
#include <hip/hip_runtime.h>
#include <math.h>

// x: [B=8, C=1, D=3, H=1536, W=1536] fp32
// out = (x - maxpool3x3x3(x) + 1e-5 > 0) ? x : 0 (pool broadcast over depth).
//
// R7: single-pass rolling-row design. Prior two-phase kernel re-read x (226 MB)
// through L3 (per-XCD L2 = 4MB can't hold 32 CUs x 442 KB of phase-1 staging),
// and its inter-phase __syncthreads drained vmcnt(0) every block. Here each of
// 384 threads owns one f4-column of a full-width 16-row strip and walks rows:
//   - depth-max m in registers
//   - vertical 3-max from a 3-deep rolling register window (m2,m1,m)
//   - horizontal halo via 2 redundant neighbor-scalar loads (guaranteed L1-hot:
//     same lines the wave's own f4 loads just fetched)
//   - x kept in registers load->store: read HBM exactly once, no LDS, NO barriers
//   - 1-row software prefetch; waves fully independent -> loads never drain.

#define Hh   1536
#define Ww   1536
#define EPSf 1e-5f
#define TH   16                 // output rows per block
#define NSTRIP (Hh / TH)        // 96 strips
#define NTHR 384                // one f4-column per thread (384*4 = 1536)

typedef float f4 __attribute__((ext_vector_type(4)));

__global__ __launch_bounds__(NTHR, 5) void nms3d_kernel(const float* __restrict__ x,
                                                        float* __restrict__ out) {
    const int t   = threadIdx.x;
    const int bid = blockIdx.x;
    const int b   = bid / NSTRIP;          // batch
    const int s   = bid - b * NSTRIP;      // strip (consecutive blocks adjacent)
    const int h0  = s * TH;

    const size_t plane = (size_t)Hh * Ww;
    const float* __restrict__ xb = x + (size_t)b * 3 * plane;
    float* __restrict__       ob = out + (size_t)b * 3 * plane;

    const float NI = -INFINITY, PIF = INFINITY;

    const int c4 = 4 * t;                                  // first col of this f4
    const int li = (t == 0) ? 0 : c4 - 1;                  // left neighbor col (clamped)
    const int ri = (t == NTHR - 1) ? Ww - 1 : c4 + 4;      // right neighbor col (clamped)
    const float lcl = (t == 0) ? NI : PIF;                 // -inf override at image edge
    const float rcl = (t == NTHR - 1) ? NI : PIF;

    // rolling state
    f4 xp0{}, xp1{}, xp2{};                 // x planes of row g-1 (next output row)
    f4 m1v{}, m2v{};                        // depth-max of rows g-1, g-2
    float m1l = NI, m2l = NI, m1r = NI, m2r = NI;

    // prefetched current row g = h0 - 1 + r
    f4 xr0, xr1, xr2;
    float nl0, nl1, nl2, nr0, nr1, nr2;
    {
        const int hc = (h0 - 1 < 0) ? 0 : h0 - 1;
        const float* p = xb + (size_t)hc * Ww;
        xr0 = *(const f4*)(p + c4);
        xr1 = *(const f4*)(p + plane + c4);
        xr2 = *(const f4*)(p + 2 * plane + c4);
        nl0 = p[li]; nl1 = p[plane + li]; nl2 = p[2 * plane + li];
        nr0 = p[ri]; nr1 = p[plane + ri]; nr2 = p[2 * plane + ri];
    }

#pragma unroll
    for (int r = 0; r < TH + 2; ++r) {
        const int g = h0 - 1 + r;
        const float bound = ((unsigned)g < (unsigned)Hh) ? PIF : NI;   // depth rows have no vertical pad

        // depth-max of row g (register-only)
        f4 m;
        m.x = fminf(fmaxf(xr0.x, fmaxf(xr1.x, xr2.x)), bound);
        m.y = fminf(fmaxf(xr0.y, fmaxf(xr1.y, xr2.y)), bound);
        m.z = fminf(fmaxf(xr0.z, fmaxf(xr1.z, xr2.z)), bound);
        m.w = fminf(fmaxf(xr0.w, fmaxf(xr1.w, xr2.w)), bound);
        const float ml = fminf(fmaxf(nl0, fmaxf(nl1, nl2)), bound);
        const float mr = fminf(fmaxf(nr0, fmaxf(nr1, nr2)), bound);

        // row g's x becomes next iteration's output-row x
        const f4 nx0 = xr0, nx1 = xr1, nx2 = xr2;

        // prefetch row g+1 (consumed next iteration; latency hidden under
        // mp/output compute + cross-wave scheduling -- no barriers anywhere)
        if (r <= TH) {
            const int gn = g + 1;
            const int hn = (gn > Hh - 1) ? Hh - 1 : gn;
            const float* p = xb + (size_t)hn * Ww;
            xr0 = *(const f4*)(p + c4);
            xr1 = *(const f4*)(p + plane + c4);
            xr2 = *(const f4*)(p + 2 * plane + c4);
            nl0 = p[li]; nl1 = p[plane + li]; nl2 = p[2 * plane + li];
            nr0 = p[ri]; nr1 = p[plane + ri]; nr2 = p[2 * plane + ri];
        }

        if (r >= 2) {
            // vertical 3-max over m rows g-2..g  -> pool row g-1
            f4 v;
            v.x = fmaxf(m2v.x, fmaxf(m1v.x, m.x));
            v.y = fmaxf(m2v.y, fmaxf(m1v.y, m.y));
            v.z = fmaxf(m2v.z, fmaxf(m1v.z, m.z));
            v.w = fmaxf(m2v.w, fmaxf(m1v.w, m.w));
            const float vl = fminf(fmaxf(m2l, fmaxf(m1l, ml)), lcl);
            const float vr = fminf(fmaxf(m2r, fmaxf(m1r, mr)), rcl);

            // horizontal 3-max
            f4 mp;
            mp.x = fmaxf(vl,  fmaxf(v.x, v.y));
            mp.y = fmaxf(v.x, fmaxf(v.y, v.z));
            mp.z = fmaxf(v.y, fmaxf(v.z, v.w));
            mp.w = fmaxf(v.z, fmaxf(v.w, vr));

            // masked write of row g-1, all 3 planes, from registers (no re-read)
            float* po = ob + (size_t)(g - 1) * Ww + c4;
            f4 o;
            o.x = ((xp0.x - mp.x) + EPSf > 0.0f) ? xp0.x : 0.0f;
            o.y = ((xp0.y - mp.y) + EPSf > 0.0f) ? xp0.y : 0.0f;
            o.z = ((xp0.z - mp.z) + EPSf > 0.0f) ? xp0.z : 0.0f;
            o.w = ((xp0.w - mp.w) + EPSf > 0.0f) ? xp0.w : 0.0f;
            __builtin_nontemporal_store(o, (f4*)po);
            o.x = ((xp1.x - mp.x) + EPSf > 0.0f) ? xp1.x : 0.0f;
            o.y = ((xp1.y - mp.y) + EPSf > 0.0f) ? xp1.y : 0.0f;
            o.z = ((xp1.z - mp.z) + EPSf > 0.0f) ? xp1.z : 0.0f;
            o.w = ((xp1.w - mp.w) + EPSf > 0.0f) ? xp1.w : 0.0f;
            __builtin_nontemporal_store(o, (f4*)(po + plane));
            o.x = ((xp2.x - mp.x) + EPSf > 0.0f) ? xp2.x : 0.0f;
            o.y = ((xp2.y - mp.y) + EPSf > 0.0f) ? xp2.y : 0.0f;
            o.z = ((xp2.z - mp.z) + EPSf > 0.0f) ? xp2.z : 0.0f;
            o.w = ((xp2.w - mp.w) + EPSf > 0.0f) ? xp2.w : 0.0f;
            __builtin_nontemporal_store(o, (f4*)(po + 2 * plane));
        }

        // rotate rolling windows (pure renaming under full unroll)
        m2v = m1v; m1v = m;
        m2l = m1l; m1l = ml;
        m2r = m1r; m1r = mr;
        xp0 = nx0; xp1 = nx1; xp2 = nx2;

        // pin iteration boundary: keeps the prefetch issued in THIS iteration
        // from being mass-hoisted across all 18 unrolled bodies (VGPR blowup)
        __builtin_amdgcn_sched_barrier(0);
    }
}

extern "C" void kernel_launch(void* const* d_in, const int* in_sizes, int n_in,
                              void* d_out, int out_size, void* d_ws, size_t ws_size,
                              hipStream_t stream) {
    const float* x = (const float*)d_in[0];
    float* out = (float*)d_out;
    const int grid = 8 * NSTRIP;   // 768 blocks, 3 per CU, batch-major
    nms3d_kernel<<<dim3(grid), dim3(NTHR), 0, stream>>>(x, out);
}

// Round 9
// 379.856 us; speedup vs baseline: 1.0225x; 1.0225x over previous
//
#include <hip/hip_runtime.h>
#include <math.h>

// x: [B=8, C=1, D=3, H=1536, W=1536] fp32
// out = (x - maxpool3x3x3(x) + 1e-5 > 0) ? x : 0 (pool broadcast over depth).
// Separable: m = depth-max over planes (LDS), mp = 3x3 spatial max of m.
//
// R8 (7th resubmit after infra failures): identical to the best-known two-phase
// full-width kernel (136 us) EXCEPT stores are plain cached stores instead of
// __builtin_nontemporal_store.
// Theory: both prior structures pinned at 2.6 TB/s HBM while the harness fill
// does 6.5 TB/s with normal stores on the same buffer. NT stores (a) must
// probe/invalidate L3-resident output lines (the fill left them cached) and
// (b) ack from HBM (~900cy) instead of L2 (~200cy), backing up vmcnt and
// throttling wave issue. Plain stores write-hit in L2/L3 with fast acks and
// deferred, overlapped writeback.

#define Hh   1536
#define Ww   1536
#define EPSf 1e-5f
#define TH   6                  // output rows per block
#define NRr  (TH + 2)           // LDS rows (with vertical halo) = 8
#define F4W  (Ww / 4)           // 384 f4 per full row
#define ROWP 1544               // [0..2] dead, [3]=left pad, [4..1539]=cols, [1540]=right pad
#define NSTRIP (Hh / TH)        // 256 strips

typedef float f4 __attribute__((ext_vector_type(4)));

__global__ __launch_bounds__(256, 3) void nms3d_kernel(const float* __restrict__ x,
                                                       float* __restrict__ out) {
    __shared__ float sm[NRr][ROWP];     // depth-max rows h0-1 .. h0+TH, 49.4 KB

    const int t = threadIdx.x;
    const int s = blockIdx.x & 255;     // strip (consecutive blocks = adjacent strips)
    const int b = blockIdx.x >> 8;      // batch

    const int h0 = s * TH;
    const size_t plane = (size_t)Hh * Ww;
    const float* xb = x + (size_t)b * 3 * plane;
    float*       ob = out + (size_t)b * 3 * plane;

    const float NI = -INFINITY, PIF = INFINITY;

    // image-edge pads (cols -1 and W) = -inf, once
    if (t < 2 * NRr) {
        const int r = t >> 1;
        sm[r][(t & 1) ? 1540 : 3] = NI;
    }

    // ---------------- Phase 1: depth-max -> LDS, sequential 4 KB bursts ------
    // 8 rows x 384 f4 = 3072 tasks = 12/thread, in 3 groups of 4.
#pragma unroll
    for (int g = 0; g < 3; ++g) {
        f4 v0[4], v1[4], v2[4];
        int rr[4], cc[4];
#pragma unroll
        for (int u = 0; u < 4; ++u) {
            const int tau = t + 256 * (g * 4 + u);
            const int r = tau / F4W;
            const int c = tau - r * F4W;
            rr[u] = r; cc[u] = c;
            const int h  = h0 - 1 + r;
            const int hc = h < 0 ? 0 : (h > Hh - 1 ? Hh - 1 : h);
            const float* p = xb + (size_t)hc * Ww + 4 * c;
            v0[u] = *(const f4*)(p);
            v1[u] = *(const f4*)(p + plane);
            v2[u] = *(const f4*)(p + 2 * plane);
        }
        // Fence: 12 loads stay issued before their consumers. Consumers are
        // LDS stores (data-dep on loads) -> cannot be IR-hoisted above them.
        __builtin_amdgcn_sched_barrier(0);
#pragma unroll
        for (int u = 0; u < 4; ++u) {
            const int h = h0 - 1 + rr[u];
            const float bound = ((unsigned)h < (unsigned)Hh) ? PIF : NI;
            f4 m;
            m.x = fminf(fmaxf(v0[u].x, fmaxf(v1[u].x, v2[u].x)), bound);
            m.y = fminf(fmaxf(v0[u].y, fmaxf(v1[u].y, v2[u].y)), bound);
            m.z = fminf(fmaxf(v0[u].z, fmaxf(v1[u].z, v2[u].z)), bound);
            m.w = fminf(fmaxf(v0[u].w, fmaxf(v1[u].w, v2[u].w)), bound);
            *(f4*)&sm[rr[u]][4 + 4 * cc[u]] = m;
        }
    }
    __syncthreads();

    // ---------------- Phase 2: pool + mask + cached store, sequential bursts -
    // 6 rows x 384 f4 = 2304 tasks = 9/thread, in 3 groups of 3.
    // x re-read is L2/L3-hot (phase 1 touched it microseconds ago).
#pragma unroll
    for (int g = 0; g < 3; ++g) {
        f4 a0[3], a1[3], a2[3];
        int rr[3], cc[3];
#pragma unroll
        for (int u = 0; u < 3; ++u) {
            const int tau = t + 256 * (g * 3 + u);
            const int r = tau / F4W;
            const int c = tau - r * F4W;
            rr[u] = r; cc[u] = c;
            const float* p = xb + (size_t)(h0 + r) * Ww + 4 * c;
            a0[u] = *(const f4*)(p);
            a1[u] = *(const f4*)(p + plane);
            a2[u] = *(const f4*)(p + 2 * plane);
        }
        __builtin_amdgcn_sched_barrier(0);
#pragma unroll
        for (int u = 0; u < 3; ++u) {
            const int r = rr[u], c = cc[u];
            // window cols 4c-1 .. 4c+4 over sm rows r..r+2, via aligned f4s
            float l = NI, w0v = NI, w1v = NI, w2v = NI, w3v = NI, rt = NI;
#pragma unroll
            for (int dr = 0; dr < 3; ++dr) {
                const float* row = &sm[r + dr][0];
                const f4 q0 = *(const f4*)&row[4 * c];       // .w = col 4c-1
                const f4 q1 = *(const f4*)&row[4 * c + 4];   // cols 4c..4c+3
                const f4 q2 = *(const f4*)&row[4 * c + 8];   // .x = col 4c+4
                l   = fmaxf(l,   q0.w);
                w0v = fmaxf(w0v, q1.x);
                w1v = fmaxf(w1v, q1.y);
                w2v = fmaxf(w2v, q1.z);
                w3v = fmaxf(w3v, q1.w);
                rt  = fmaxf(rt,  q2.x);
            }
            f4 mp;
            mp.x = fmaxf(l,   fmaxf(w0v, w1v));
            mp.y = fmaxf(w0v, fmaxf(w1v, w2v));
            mp.z = fmaxf(w1v, fmaxf(w2v, w3v));
            mp.w = fmaxf(w2v, fmaxf(w3v, rt));

            float* po = ob + (size_t)(h0 + r) * Ww + 4 * c;
            f4 o;
            o.x = ((a0[u].x - mp.x) + EPSf > 0.0f) ? a0[u].x : 0.0f;
            o.y = ((a0[u].y - mp.y) + EPSf > 0.0f) ? a0[u].y : 0.0f;
            o.z = ((a0[u].z - mp.z) + EPSf > 0.0f) ? a0[u].z : 0.0f;
            o.w = ((a0[u].w - mp.w) + EPSf > 0.0f) ? a0[u].w : 0.0f;
            *(f4*)po = o;
            o.x = ((a1[u].x - mp.x) + EPSf > 0.0f) ? a1[u].x : 0.0f;
            o.y = ((a1[u].y - mp.y) + EPSf > 0.0f) ? a1[u].y : 0.0f;
            o.z = ((a1[u].z - mp.z) + EPSf > 0.0f) ? a1[u].z : 0.0f;
            o.w = ((a1[u].w - mp.w) + EPSf > 0.0f) ? a1[u].w : 0.0f;
            *(f4*)(po + plane) = o;
            o.x = ((a2[u].x - mp.x) + EPSf > 0.0f) ? a2[u].x : 0.0f;
            o.y = ((a2[u].y - mp.y) + EPSf > 0.0f) ? a2[u].y : 0.0f;
            o.z = ((a2[u].z - mp.z) + EPSf > 0.0f) ? a2[u].z : 0.0f;
            o.w = ((a2[u].w - mp.w) + EPSf > 0.0f) ? a2[u].w : 0.0f;
            *(f4*)(po + 2 * plane) = o;
        }
    }
}

extern "C" void kernel_launch(void* const* d_in, const int* in_sizes, int n_in,
                              void* d_out, int out_size, void* d_ws, size_t ws_size,
                              hipStream_t stream) {
    const float* x = (const float*)d_in[0];
    float* out = (float*)d_out;
    const int grid = 8 * NSTRIP;   // 2048 blocks, natural (batch-major) order
    nms3d_kernel<<<dim3(grid), dim3(256), 0, stream>>>(x, out);
}

// Round 10
// 372.693 us; speedup vs baseline: 1.0421x; 1.0192x over previous
//
#include <hip/hip_runtime.h>
#include <math.h>

// x: [B=8, C=1, D=3, H=1536, W=1536] fp32
// out = (x - maxpool3x3x3(x) + 1e-5 > 0) ? x : 0 (pool broadcast over depth).
// Separable: m = depth-max over planes (LDS), mp = 3x3 spatial max of m.
//
// R9: single-read, batched-load/batched-store structure.
// Post-mortem R8: NT->cached stores was ~neutral -> NT theory dead. Remaining
// shared defect of all ~135us structures: (a) vmcnt retires IN ORDER, so any
// load-consuming waitcnt issued after stores also waits for those stores'
// acks (phase2 group boundaries each ate a store round trip); (b) the rolling
// kernel's prefetch collapsed (VGPR=36 proves loads were sunk to consumers).
// This kernel: 384 thr/block, thread t owns f4-column 4t. Phase 1 issues ALL
// 24 loads (8 rows x 3 planes) to registers up front (no store in any load
// wait chain; LDS writes are lgkmcnt), depth-max -> LDS, one barrier. Phase 2
// computes 6 mp rows from LDS and masks x FROM REGISTERS (no re-read), then
// issues all 18 stores at the end (plane-major, long sequential runs). No
// load waits behind a store anywhere.

#define Hh   1536
#define Ww   1536
#define EPSf 1e-5f
#define TH   6                  // output rows per block
#define NRr  (TH + 2)           // LDS rows (with vertical halo) = 8
#define ROWP 1544               // [0..2] dead, [3]=left pad, [4..1539]=cols, [1540]=right pad
#define NSTRIP (Hh / TH)        // 256 strips
#define NTHR 384                // one f4-column per thread

typedef float f4 __attribute__((ext_vector_type(4)));

__global__ __launch_bounds__(NTHR, 3) void nms3d_kernel(const float* __restrict__ x,
                                                        float* __restrict__ out) {
    __shared__ float sm[NRr][ROWP];     // depth-max rows h0-1 .. h0+TH, 49.4 KB

    const int t = threadIdx.x;
    const int s = blockIdx.x & 255;     // strip (consecutive blocks = adjacent strips)
    const int b = blockIdx.x >> 8;      // batch

    const int h0 = s * TH;
    const size_t plane = (size_t)Hh * Ww;
    const float* xb = x + (size_t)b * 3 * plane;
    float*       ob = out + (size_t)b * 3 * plane;

    const float NI = -INFINITY, PIF = INFINITY;

    // image-edge pads (cols -1 and W) = -inf, once
    if (t < 2 * NRr) {
        const int r = t >> 1;
        sm[r][(t & 1) ? 1540 : 3] = NI;
    }

    // ---------------- Phase 1: 24 loads up front, depth-max -> LDS ----------
    // Per row r (image row h0-1+r, clamped), block reads a full 6 KB row per
    // plane: 384 thr x 16 B contiguous. All loads issued before any consumer.
    f4 xv[NRr][3];
#pragma unroll
    for (int r = 0; r < NRr; ++r) {
        const int h  = h0 - 1 + r;
        const int hc = h < 0 ? 0 : (h > Hh - 1 ? Hh - 1 : h);
        const float* p = xb + (size_t)hc * Ww + 4 * t;
        xv[r][0] = *(const f4*)(p);
        xv[r][1] = *(const f4*)(p + plane);
        xv[r][2] = *(const f4*)(p + 2 * plane);
    }
    // Fence: keep all 24 loads issued before consumers (consumers are
    // data-dependent LDS stores -> cannot be hoisted above the loads).
    __builtin_amdgcn_sched_barrier(0);

#pragma unroll
    for (int r = 0; r < NRr; ++r) {
        const int h = h0 - 1 + r;
        const float bound = ((unsigned)h < (unsigned)Hh) ? PIF : NI;
        f4 m;
        m.x = fminf(fmaxf(xv[r][0].x, fmaxf(xv[r][1].x, xv[r][2].x)), bound);
        m.y = fminf(fmaxf(xv[r][0].y, fmaxf(xv[r][1].y, xv[r][2].y)), bound);
        m.z = fminf(fmaxf(xv[r][0].z, fmaxf(xv[r][1].z, xv[r][2].z)), bound);
        m.w = fminf(fmaxf(xv[r][0].w, fmaxf(xv[r][1].w, xv[r][2].w)), bound);
        *(f4*)&sm[r][4 + 4 * t] = m;    // conflict-free: lane stride 16B
    }
    __syncthreads();

    // ---------------- Phase 2: mp from LDS, mask register-x, batched stores -
    f4 mpv[TH];
#pragma unroll
    for (int rr = 0; rr < TH; ++rr) {
        // window cols 4t-1 .. 4t+4 over sm rows rr..rr+2, via aligned f4s
        float l = NI, w0v = NI, w1v = NI, w2v = NI, w3v = NI, rt = NI;
#pragma unroll
        for (int dr = 0; dr < 3; ++dr) {
            const float* row = &sm[rr + dr][0];
            const f4 q0 = *(const f4*)&row[4 * t];       // .w = col 4t-1
            const f4 q1 = *(const f4*)&row[4 * t + 4];   // cols 4t..4t+3
            const f4 q2 = *(const f4*)&row[4 * t + 8];   // .x = col 4t+4
            l   = fmaxf(l,   q0.w);
            w0v = fmaxf(w0v, q1.x);
            w1v = fmaxf(w1v, q1.y);
            w2v = fmaxf(w2v, q1.z);
            w3v = fmaxf(w3v, q1.w);
            rt  = fmaxf(rt,  q2.x);
        }
        mpv[rr].x = fmaxf(l,   fmaxf(w0v, w1v));
        mpv[rr].y = fmaxf(w0v, fmaxf(w1v, w2v));
        mpv[rr].z = fmaxf(w1v, fmaxf(w2v, w3v));
        mpv[rr].w = fmaxf(w2v, fmaxf(w3v, rt));
    }

    // All 18 stores at the end, plane-major: per plane a block emits 6
    // consecutive full rows (36 KB sequential). No load ever waits on these.
#pragma unroll
    for (int d = 0; d < 3; ++d) {
        float* pd = ob + (size_t)d * plane + (size_t)h0 * Ww + 4 * t;
#pragma unroll
        for (int rr = 0; rr < TH; ++rr) {
            const f4 a = xv[rr + 1][d];          // x held in registers since phase 1
            const f4 mp = mpv[rr];
            f4 o;
            o.x = ((a.x - mp.x) + EPSf > 0.0f) ? a.x : 0.0f;
            o.y = ((a.y - mp.y) + EPSf > 0.0f) ? a.y : 0.0f;
            o.z = ((a.z - mp.z) + EPSf > 0.0f) ? a.z : 0.0f;
            o.w = ((a.w - mp.w) + EPSf > 0.0f) ? a.w : 0.0f;
            *(f4*)(pd + (size_t)rr * Ww) = o;
        }
    }
}

extern "C" void kernel_launch(void* const* d_in, const int* in_sizes, int n_in,
                              void* d_out, int out_size, void* d_ws, size_t ws_size,
                              hipStream_t stream) {
    const float* x = (const float*)d_in[0];
    float* out = (float*)d_out;
    const int grid = 8 * NSTRIP;   // 2048 blocks, natural (batch-major) order
    nms3d_kernel<<<dim3(grid), dim3(NTHR), 0, stream>>>(x, out);
}